// Round 1
// baseline (608.018 us; speedup 1.0000x reference)
//
#include <hip/hip_runtime.h>

typedef _Float16 f16;
typedef _Float16 half8 __attribute__((ext_vector_type(8)));
typedef _Float16 half4 __attribute__((ext_vector_type(4)));
typedef float f32x4 __attribute__((ext_vector_type(4)));

#define NTOK 343
#define NHEADS 12
#define NBATCH 128
#define HD 32
#define KDIM 384
#define VT_STRIDE 384
#define NPAIR (NTOK*NTOK)

// ---------------- K0: fp32 -> fp16 convert (vectorized) ----------------
__global__ __launch_bounds__(256) void cvt_f32_f16(const float* __restrict__ src,
                                                   f16* __restrict__ dst, int n4) {
  int stride = gridDim.x * blockDim.x;
  for (int i = blockIdx.x * blockDim.x + threadIdx.x; i < n4; i += stride) {
    float4 v = reinterpret_cast<const float4*>(src)[i];
    half4 h;
    h[0] = (f16)v.x; h[1] = (f16)v.y; h[2] = (f16)v.z; h[3] = (f16)v.w;
    reinterpret_cast<half4*>(dst)[i] = h;
  }
}

// ---------------- K0b: expand bias_table via rel_index to [h][q][kv] f16 ----------------
__global__ __launch_bounds__(256) void bias_expand(const float* __restrict__ table,
                                                   const int* __restrict__ rel,
                                                   f16* __restrict__ out) {
  int pair = blockIdx.x * blockDim.x + threadIdx.x;
  if (pair >= NPAIR) return;
  int idx = rel[pair];
  #pragma unroll
  for (int h = 0; h < NHEADS; ++h)
    out[(size_t)h * NPAIR + pair] = (f16)table[idx * NHEADS + h];
}

// ---------------- shared 128x128 GEMM body (A[M][384] f16, Bw[N][384] f16) ----------------
// 4 waves (2x2), each wave 64x64 = 4x4 frags of 16x16, K-step 64, mfma_f32_16x16x32_f16.
// A-frag: lane holds A[row=l&15][k=(l>>4)*8+e]; B-frag: B^T row-major, same pattern. (m89/m97 layouts)
__device__ __forceinline__ void gemm128_body(const f16* __restrict__ A,
                                             const f16* __restrict__ Bw,
                                             int mtile, int ntile,
                                             f32x4 acc[4][4]) {
  __shared__ f16 As[128][72];  // pad to 72 f16 (144B rows) -> 2-way bank conflicts only
  __shared__ f16 Bs[128][72];
  const int tid = threadIdx.x;
  const int lane = tid & 63;
  const int wave = tid >> 6;
  const int wm = wave >> 1, wn = wave & 1;

  #pragma unroll
  for (int i = 0; i < 4; ++i)
    #pragma unroll
    for (int j = 0; j < 4; ++j) { f32x4 z = {0.f,0.f,0.f,0.f}; acc[i][j] = z; }

  const int row0 = tid >> 3;       // 0..31
  const int chunk = tid & 7;       // 8 chunks of 8 f16 = 64 f16 per row
  for (int k0 = 0; k0 < KDIM; k0 += 64) {
    float4 av[4], bv[4];
    #pragma unroll
    for (int i = 0; i < 4; ++i) {
      int row = row0 + i * 32;
      av[i] = *reinterpret_cast<const float4*>(A + (size_t)(mtile*128 + row)*KDIM + k0 + chunk*8);
      bv[i] = *reinterpret_cast<const float4*>(Bw + (size_t)(ntile*128 + row)*KDIM + k0 + chunk*8);
    }
    __syncthreads();               // previous compute done before overwrite
    #pragma unroll
    for (int i = 0; i < 4; ++i) {
      int row = row0 + i * 32;
      *reinterpret_cast<float4*>(&As[row][chunk*8]) = av[i];
      *reinterpret_cast<float4*>(&Bs[row][chunk*8]) = bv[i];
    }
    __syncthreads();
    #pragma unroll
    for (int kk = 0; kk < 2; ++kk) {
      half8 af[4], bf[4];
      #pragma unroll
      for (int mi = 0; mi < 4; ++mi)
        af[mi] = *reinterpret_cast<half8*>(&As[wm*64 + mi*16 + (lane & 15)][kk*32 + (lane >> 4)*8]);
      #pragma unroll
      for (int ni = 0; ni < 4; ++ni)
        bf[ni] = *reinterpret_cast<half8*>(&Bs[wn*64 + ni*16 + (lane & 15)][kk*32 + (lane >> 4)*8]);
      #pragma unroll
      for (int mi = 0; mi < 4; ++mi)
        #pragma unroll
        for (int ni = 0; ni < 4; ++ni)
          acc[mi][ni] = __builtin_amdgcn_mfma_f32_16x16x32_f16(af[mi], bf[ni], acc[mi][ni], 0, 0, 0);
    }
  }
}

// ---------------- K1: QKV GEMM + bias + scatter to q / k / v^T (f16) ----------------
__global__ __launch_bounds__(256) void qkv_gemm(const f16* __restrict__ xb,
                                                const f16* __restrict__ wq,
                                                const float* __restrict__ qkv_b,
                                                f16* __restrict__ qh,
                                                f16* __restrict__ kh,
                                                f16* __restrict__ vt) {
  const int ntile = blockIdx.x, mtile = blockIdx.y;
  f32x4 acc[4][4];
  gemm128_body(xb, wq, mtile, ntile, acc);
  const int lane = threadIdx.x & 63;
  const int wave = threadIdx.x >> 6;
  const int wm = wave >> 1, wn = wave & 1;
  const float scale = 0.17677669529663687f;  // 32^-0.5
  #pragma unroll
  for (int ni = 0; ni < 4; ++ni) {
    int j = ntile*128 + wn*64 + ni*16 + (lane & 15);
    float bj = qkv_b[j];
    int which = j / KDIM;
    int rem = j % KDIM;
    int h = rem >> 5, d = rem & 31;
    #pragma unroll
    for (int mi = 0; mi < 4; ++mi) {
      #pragma unroll
      for (int r = 0; r < 4; ++r) {
        int m = mtile*128 + wm*64 + mi*16 + (lane >> 4)*4 + r;
        unsigned int b = (unsigned int)m / NTOK;
        unsigned int n = (unsigned int)m % NTOK;
        float v = acc[mi][ni][r] + bj;
        size_t bh = (size_t)b * NHEADS + h;
        if (which == 0)      qh[(bh*NTOK + n)*HD + d] = (f16)(v * scale);
        else if (which == 1) kh[(bh*NTOK + n)*HD + d] = (f16)v;
        else                 vt[(bh*HD + d)*VT_STRIDE + n] = (f16)v;
      }
    }
  }
}

// ---------------- K2: fused flash attention per (qtile, h, b) ----------------
// block: 256 thr = 4 waves; wave owns 16 q-rows. KV tiles of 64.
__global__ __launch_bounds__(256) void attn_kernel(const f16* __restrict__ qh,
                                                   const f16* __restrict__ kh,
                                                   const f16* __restrict__ vt,
                                                   const f16* __restrict__ biasf,
                                                   f16* __restrict__ ab) {
  __shared__ f16 Qs[64][40];
  __shared__ f16 Ks[64][40];
  __shared__ f16 Vs[32][72];
  __shared__ f16 Ps[64][72];
  const int tid = threadIdx.x;
  const int lane = tid & 63;
  const int wave = tid >> 6;
  const int qt = blockIdx.x;
  const int h = blockIdx.y;
  const int b = blockIdx.z;
  const size_t bh = (size_t)b * NHEADS + h;

  // stage Q tile (64 rows x 32 d): thread -> (row=tid>>2, chunk=tid&3)
  {
    int row = tid >> 2, chunk = tid & 3;
    int n = qt*64 + row; n = n < NTOK ? n : NTOK - 1;
    *reinterpret_cast<float4*>(&Qs[row][chunk*8]) =
        *reinterpret_cast<const float4*>(qh + (bh*NTOK + n)*HD + chunk*8);
  }
  __syncthreads();
  half8 aq = *reinterpret_cast<half8*>(&Qs[wave*16 + (lane & 15)][(lane >> 4)*8]);

  float m_run[4], l_run[4];
  f32x4 o0 = {0.f,0.f,0.f,0.f}, o1 = {0.f,0.f,0.f,0.f};
  #pragma unroll
  for (int r = 0; r < 4; ++r) { m_run[r] = -3.0e38f; l_run[r] = 0.f; }

  for (int kvt = 0; kvt < 6; ++kvt) {
    { // stage K tile (64x32) and V^T tile (32x64)
      int row = tid >> 2, chunk = tid & 3;
      int kv = kvt*64 + row; int n = kv < NTOK ? kv : NTOK - 1;
      *reinterpret_cast<float4*>(&Ks[row][chunk*8]) =
          *reinterpret_cast<const float4*>(kh + (bh*NTOK + n)*HD + chunk*8);
      int d = tid >> 3, c2 = tid & 7;
      *reinterpret_cast<float4*>(&Vs[d][c2*8]) =
          *reinterpret_cast<const float4*>(vt + (bh*HD + d)*VT_STRIDE + kvt*64 + c2*8);
    }
    __syncthreads();

    // S = Q @ K^T : 4 n-frags of 16x16 per wave
    f32x4 s[4];
    #pragma unroll
    for (int nt = 0; nt < 4; ++nt) {
      half8 bk = *reinterpret_cast<half8*>(&Ks[nt*16 + (lane & 15)][(lane >> 4)*8]);
      f32x4 z = {0.f,0.f,0.f,0.f};
      s[nt] = __builtin_amdgcn_mfma_f32_16x16x32_f16(aq, bk, z, 0, 0, 0);
    }

    // bias + mask
    float sv[4][4]; float rmax[4];
    #pragma unroll
    for (int r = 0; r < 4; ++r) rmax[r] = -3.0e38f;
    #pragma unroll
    for (int nt = 0; nt < 4; ++nt) {
      int kv = kvt*64 + nt*16 + (lane & 15);
      int kvc = kv < NTOK ? kv : NTOK - 1;
      bool kvok = kv < NTOK;
      #pragma unroll
      for (int r = 0; r < 4; ++r) {
        int q = qt*64 + wave*16 + (lane >> 4)*4 + r;
        int qc = q < NTOK ? q : NTOK - 1;
        float x = s[nt][r] + (float)biasf[(size_t)h*NPAIR + (size_t)qc*NTOK + kvc];
        x = kvok ? x : -1.0e30f;
        sv[nt][r] = x;
        rmax[r] = fmaxf(rmax[r], x);
      }
    }
    // row max across 16 lanes (same l>>4 group)
    #pragma unroll
    for (int r = 0; r < 4; ++r) {
      float v = rmax[r];
      v = fmaxf(v, __shfl_xor(v, 1));
      v = fmaxf(v, __shfl_xor(v, 2));
      v = fmaxf(v, __shfl_xor(v, 4));
      v = fmaxf(v, __shfl_xor(v, 8));
      rmax[r] = v;
    }
    // online softmax update; write P to LDS (intra-wave rows only)
    #pragma unroll
    for (int r = 0; r < 4; ++r) {
      float mnew = fmaxf(m_run[r], rmax[r]);
      float sf = __expf(m_run[r] - mnew);
      m_run[r] = mnew;
      l_run[r] *= sf;
      o0[r] *= sf; o1[r] *= sf;
      float rs = 0.f;
      int qrow = wave*16 + (lane >> 4)*4 + r;
      #pragma unroll
      for (int nt = 0; nt < 4; ++nt) {
        float p = __expf(sv[nt][r] - mnew);
        rs += p;
        Ps[qrow][nt*16 + (lane & 15)] = (f16)p;
      }
      rs += __shfl_xor(rs, 1);
      rs += __shfl_xor(rs, 2);
      rs += __shfl_xor(rs, 4);
      rs += __shfl_xor(rs, 8);
      l_run[r] += rs;
    }

    // PV: O += P @ V  (P re-fragmented via LDS; same-wave rows, no barrier needed)
    half8 ap0 = *reinterpret_cast<half8*>(&Ps[wave*16 + (lane & 15)][(lane >> 4)*8]);
    half8 ap1 = *reinterpret_cast<half8*>(&Ps[wave*16 + (lane & 15)][32 + (lane >> 4)*8]);
    half8 bv;
    bv = *reinterpret_cast<half8*>(&Vs[(lane & 15)][(lane >> 4)*8]);
    o0 = __builtin_amdgcn_mfma_f32_16x16x32_f16(ap0, bv, o0, 0, 0, 0);
    bv = *reinterpret_cast<half8*>(&Vs[(lane & 15)][32 + (lane >> 4)*8]);
    o0 = __builtin_amdgcn_mfma_f32_16x16x32_f16(ap1, bv, o0, 0, 0, 0);
    bv = *reinterpret_cast<half8*>(&Vs[16 + (lane & 15)][(lane >> 4)*8]);
    o1 = __builtin_amdgcn_mfma_f32_16x16x32_f16(ap0, bv, o1, 0, 0, 0);
    bv = *reinterpret_cast<half8*>(&Vs[16 + (lane & 15)][32 + (lane >> 4)*8]);
    o1 = __builtin_amdgcn_mfma_f32_16x16x32_f16(ap1, bv, o1, 0, 0, 0);
    __syncthreads();  // all waves done with Ks/Vs before restage
  }

  // epilogue: normalize + store to ab[b][q][h*32 + d] (f16)
  #pragma unroll
  for (int r = 0; r < 4; ++r) {
    int q = qt*64 + wave*16 + (lane >> 4)*4 + r;
    if (q < NTOK) {
      float inv = 1.f / l_run[r];
      size_t base = ((size_t)b*NTOK + q)*KDIM + h*HD;
      ab[base + (lane & 15)]      = (f16)(o0[r] * inv);
      ab[base + 16 + (lane & 15)] = (f16)(o1[r] * inv);
    }
  }
}

// ---------------- K3: output projection GEMM + bias (fp32 out) ----------------
__global__ __launch_bounds__(256) void proj_gemm(const f16* __restrict__ ab,
                                                 const f16* __restrict__ wp,
                                                 const float* __restrict__ proj_b,
                                                 float* __restrict__ out) {
  const int ntile = blockIdx.x, mtile = blockIdx.y;
  f32x4 acc[4][4];
  gemm128_body(ab, wp, mtile, ntile, acc);
  const int lane = threadIdx.x & 63;
  const int wave = threadIdx.x >> 6;
  const int wm = wave >> 1, wn = wave & 1;
  #pragma unroll
  for (int ni = 0; ni < 4; ++ni) {
    int j = ntile*128 + wn*64 + ni*16 + (lane & 15);
    float pb = proj_b[j];
    #pragma unroll
    for (int mi = 0; mi < 4; ++mi) {
      #pragma unroll
      for (int r = 0; r < 4; ++r) {
        int m = mtile*128 + wm*64 + mi*16 + (lane >> 4)*4 + r;
        out[(size_t)m*KDIM + j] = acc[mi][ni][r] + pb;
      }
    }
  }
}

// ---------------- host ----------------
extern "C" void kernel_launch(void* const* d_in, const int* in_sizes, int n_in,
                              void* d_out, int out_size, void* d_ws, size_t ws_size,
                              hipStream_t stream) {
  const float* x          = (const float*)d_in[0];
  const float* qkv_w      = (const float*)d_in[1];
  const float* qkv_b      = (const float*)d_in[2];
  const float* proj_w     = (const float*)d_in[3];
  const float* proj_b     = (const float*)d_in[4];
  const float* bias_table = (const float*)d_in[5];
  const int*   rel_index  = (const int*)d_in[6];

  const size_t M = (size_t)NBATCH * NTOK;        // 43904
  char* p = (char*)d_ws;
  auto alloc = [&](size_t bytes) { void* r = (void*)p; p += (bytes + 255) & ~(size_t)255; return r; };
  f16* xb = (f16*)alloc(M * KDIM * 2);                         // x as f16
  f16* wq = (f16*)alloc((size_t)3 * KDIM * KDIM * 2);          // qkv_w f16
  f16* wp = (f16*)alloc((size_t)KDIM * KDIM * 2);              // proj_w f16
  f16* qh = (f16*)alloc((size_t)NBATCH*NHEADS*NTOK*HD * 2);    // q (scaled)
  f16* kh = (f16*)alloc((size_t)NBATCH*NHEADS*NTOK*HD * 2);    // k
  f16* vt = (f16*)alloc((size_t)NBATCH*NHEADS*HD*VT_STRIDE*2); // v transposed, padded
  f16* bf = (f16*)alloc((size_t)NHEADS * NPAIR * 2);           // bias[h][q][kv]
  f16* ab = (f16*)alloc(M * KDIM * 2);                         // attention output

  cvt_f32_f16<<<4096, 256, 0, stream>>>(x, xb, (int)(M * KDIM / 4));
  cvt_f32_f16<<<432, 256, 0, stream>>>(qkv_w, wq, 3 * KDIM * KDIM / 4);
  cvt_f32_f16<<<144, 256, 0, stream>>>(proj_w, wp, KDIM * KDIM / 4);
  bias_expand<<<(NPAIR + 255) / 256, 256, 0, stream>>>(bias_table, rel_index, bf);
  qkv_gemm<<<dim3(9, 343), 256, 0, stream>>>(xb, wq, qkv_b, qh, kh, vt);
  attn_kernel<<<dim3(6, NHEADS, NBATCH), 256, 0, stream>>>(qh, kh, vt, bf, ab);
  proj_gemm<<<dim3(3, 343), 256, 0, stream>>>(ab, wp, proj_b, (float*)d_out);
}

// Round 2
// 444.312 us; speedup vs baseline: 1.3684x; 1.3684x over previous
//
#include <hip/hip_runtime.h>

typedef _Float16 f16;
typedef _Float16 half8 __attribute__((ext_vector_type(8)));
typedef _Float16 half4 __attribute__((ext_vector_type(4)));
typedef float f32x4 __attribute__((ext_vector_type(4)));

#define NTOK 343
#define NHEADS 12
#define NBATCH 128
#define HD 32
#define KDIM 384
#define QKV_LD 1152
#define BIAS_LD 384

static __device__ __forceinline__ void gload16(const f16* g, f16* l) {
  __builtin_amdgcn_global_load_lds((const __attribute__((address_space(1))) void*)g,
                                   (__attribute__((address_space(3))) void*)l, 16, 0, 0);
}

// ---------------- K0: fp32 -> fp16 convert ----------------
__global__ __launch_bounds__(256) void cvt_f32_f16(const float* __restrict__ src,
                                                   f16* __restrict__ dst, int n4) {
  int stride = gridDim.x * blockDim.x;
  for (int i = blockIdx.x * blockDim.x + threadIdx.x; i < n4; i += stride) {
    float4 v = reinterpret_cast<const float4*>(src)[i];
    half4 h;
    h[0] = (f16)v.x; h[1] = (f16)v.y; h[2] = (f16)v.z; h[3] = (f16)v.w;
    reinterpret_cast<half4*>(dst)[i] = h;
  }
}

// ---------------- K0b: bias expand -> bfp[h][343][384] f16 (padded, coalesced) ----------------
__global__ __launch_bounds__(384) void bias_expand(const float* __restrict__ table,
                                                   const int* __restrict__ rel,
                                                   f16* __restrict__ out) {
  int q = blockIdx.x, h = blockIdx.y, kv = threadIdx.x;  // kv in [0,384)
  int kvc = kv < NTOK ? kv : NTOK - 1;
  int idx = rel[q * NTOK + kvc];
  f16 v = (kv < NTOK) ? (f16)table[idx * NHEADS + h] : (f16)0.f;
  out[((size_t)h * NTOK + q) * BIAS_LD + kv] = v;
}

// ---------------- 128x128 GEMM body: global_load_lds staging, linear LDS [128][64] ----------------
// 4 waves (2x2), each wave 64x64 = 4x4 frags of 16x16, mfma_f32_16x16x32_f16.
__device__ __forceinline__ void gemm128_body(const f16* __restrict__ A,
                                             const f16* __restrict__ Bw,
                                             int mtile, int ntile,
                                             f32x4 acc[4][4],
                                             f16* As, f16* Bs) {
  const int tid = threadIdx.x;
  const int lane = tid & 63;
  const int w = tid >> 6;
  const int wm = w >> 1, wn = w & 1;

  #pragma unroll
  for (int i = 0; i < 4; ++i)
    #pragma unroll
    for (int j = 0; j < 4; ++j) { f32x4 z = {0.f,0.f,0.f,0.f}; acc[i][j] = z; }

  const int lrow = w * 8 + (lane >> 3);     // + rnd*32
  const int lcol = (lane & 7) * 8;
  const f16* Ab = A + (size_t)(mtile*128 + lrow) * KDIM + lcol;
  const f16* Bb = Bw + (size_t)(ntile*128 + lrow) * KDIM + lcol;

  for (int k0 = 0; k0 < KDIM; k0 += 64) {
    __syncthreads();  // all waves done reading LDS from previous step
    #pragma unroll
    for (int rnd = 0; rnd < 4; ++rnd) {
      gload16(Ab + (size_t)rnd*32*KDIM + k0, As + rnd*2048 + w*512);
      gload16(Bb + (size_t)rnd*32*KDIM + k0, Bs + rnd*2048 + w*512);
    }
    __syncthreads();  // compiler drains vmcnt before barrier
    #pragma unroll
    for (int kk = 0; kk < 2; ++kk) {
      half8 af[4], bf[4];
      #pragma unroll
      for (int mi = 0; mi < 4; ++mi)
        af[mi] = *reinterpret_cast<half8*>(&As[(wm*64 + mi*16 + (lane & 15))*64 + kk*32 + (lane >> 4)*8]);
      #pragma unroll
      for (int ni = 0; ni < 4; ++ni)
        bf[ni] = *reinterpret_cast<half8*>(&Bs[(wn*64 + ni*16 + (lane & 15))*64 + kk*32 + (lane >> 4)*8]);
      #pragma unroll
      for (int mi = 0; mi < 4; ++mi)
        #pragma unroll
        for (int ni = 0; ni < 4; ++ni)
          acc[mi][ni] = __builtin_amdgcn_mfma_f32_16x16x32_f16(af[mi], bf[ni], acc[mi][ni], 0, 0, 0);
    }
  }
}

// ---------------- K1: QKV GEMM -> qkvb[m][1152] f16, coalesced via LDS bounce ----------------
__global__ __launch_bounds__(256) void qkv_gemm(const f16* __restrict__ xb,
                                                const f16* __restrict__ wq,
                                                const float* __restrict__ qkv_b,
                                                f16* __restrict__ qkvb) {
  __shared__ __align__(16) f16 smem[17408];   // 34816 B: staging 32KB, C-bounce 128x136
  f16* As = smem;
  f16* Bs = smem + 8192;
  const int ntile = blockIdx.x, mtile = blockIdx.y;
  f32x4 acc[4][4];
  gemm128_body(xb, wq, mtile, ntile, acc, As, Bs);

  const int tid = threadIdx.x;
  const int lane = tid & 63;
  const int w = tid >> 6;
  const int wm = w >> 1, wn = w & 1;
  const float scale = (ntile < 3) ? 0.17677669529663687f : 1.0f;  // q-part scaled

  float bj[4];
  #pragma unroll
  for (int ni = 0; ni < 4; ++ni)
    bj[ni] = qkv_b[ntile*128 + wn*64 + ni*16 + (lane & 15)];

  __syncthreads();  // done with As/Bs; reuse as C tile [128][136]
  f16* Cs = smem;
  #pragma unroll
  for (int ni = 0; ni < 4; ++ni) {
    int col = wn*64 + ni*16 + (lane & 15);
    #pragma unroll
    for (int mi = 0; mi < 4; ++mi)
      #pragma unroll
      for (int r = 0; r < 4; ++r) {
        int row = wm*64 + mi*16 + (lane >> 4)*4 + r;
        Cs[row*136 + col] = (f16)((acc[mi][ni][r] + bj[ni]) * scale);
      }
  }
  __syncthreads();
  #pragma unroll
  for (int p = 0; p < 8; ++p) {
    int row = p*16 + (tid >> 4);
    int col = (tid & 15) * 8;
    float4 v = *reinterpret_cast<float4*>(&Cs[row*136 + col]);
    *reinterpret_cast<float4*>(&qkvb[(size_t)(mtile*128 + row)*QKV_LD + ntile*128 + col]) = v;
  }
}

// ---------------- K1b: V transpose: qkvb v-part -> vt[(b,h,d)][384] ----------------
__global__ __launch_bounds__(256) void vtrans(const f16* __restrict__ qkvb,
                                              f16* __restrict__ vt) {
  __shared__ __align__(16) f16 T[64][40];
  const int tid = threadIdx.x;
  const int nt = blockIdx.x, h = blockIdx.y, b = blockIdx.z;
  {
    int row = tid >> 2, ch = tid & 3;
    int n = nt*64 + row; int nc = n < NTOK ? n : NTOK - 1;
    *reinterpret_cast<float4*>(&T[row][ch*8]) =
        *reinterpret_cast<const float4*>(&qkvb[((size_t)b*NTOK + nc)*QKV_LD + 2*KDIM + h*HD + ch*8]);
  }
  __syncthreads();
  int d = tid >> 3, c2 = tid & 7;
  half8 o;
  #pragma unroll
  for (int e = 0; e < 8; ++e) o[e] = T[c2*8 + e][d];
  *reinterpret_cast<half8*>(&vt[((size_t)(b*NHEADS + h)*HD + d)*KDIM + nt*64 + c2*8]) = o;
}

// ---------------- K2: fused flash attention per (qtile, h, b) ----------------
__global__ __launch_bounds__(256) void attn_kernel(const f16* __restrict__ qkvb,
                                                   const f16* __restrict__ vt,
                                                   const f16* __restrict__ bfp,
                                                   f16* __restrict__ ab) {
  __shared__ __align__(16) f16 Qs[64][40];
  __shared__ __align__(16) f16 Ks[64][40];
  __shared__ __align__(16) f16 Vs[32][72];
  __shared__ __align__(16) f16 Ps[64][72];
  __shared__ __align__(16) f16 Bb[64][72];
  const int tid = threadIdx.x;
  const int lane = tid & 63;
  const int wave = tid >> 6;
  const int qt = blockIdx.x;
  const int h = blockIdx.y;
  const int b = blockIdx.z;
  const size_t bh = (size_t)b * NHEADS + h;

  {  // stage Q tile (64 x 32) from qkvb
    int row = tid >> 2, ch = tid & 3;
    int n = qt*64 + row; int nc = n < NTOK ? n : NTOK - 1;
    *reinterpret_cast<float4*>(&Qs[row][ch*8]) =
        *reinterpret_cast<const float4*>(&qkvb[((size_t)b*NTOK + nc)*QKV_LD + h*HD + ch*8]);
  }
  __syncthreads();
  half8 aq = *reinterpret_cast<half8*>(&Qs[wave*16 + (lane & 15)][(lane >> 4)*8]);

  float m_run[4], l_run[4];
  f32x4 o0 = {0.f,0.f,0.f,0.f}, o1 = {0.f,0.f,0.f,0.f};
  #pragma unroll
  for (int r = 0; r < 4; ++r) { m_run[r] = -3.0e38f; l_run[r] = 0.f; }

  for (int kvt = 0; kvt < 6; ++kvt) {
    {  // stage K (64x32), V^T (32x64), bias tile (64x64)
      int row = tid >> 2, ch = tid & 3;
      int kv = kvt*64 + row; int n = kv < NTOK ? kv : NTOK - 1;
      *reinterpret_cast<float4*>(&Ks[row][ch*8]) =
          *reinterpret_cast<const float4*>(&qkvb[((size_t)b*NTOK + n)*QKV_LD + KDIM + h*HD + ch*8]);
      int d = tid >> 3, c2 = tid & 7;
      *reinterpret_cast<float4*>(&Vs[d][c2*8]) =
          *reinterpret_cast<const float4*>(&vt[(bh*HD + d)*KDIM + kvt*64 + c2*8]);
      #pragma unroll
      for (int i = 0; i < 2; ++i) {
        int brow = (tid >> 3) + i*32;       // q-local 0..63
        int q = qt*64 + brow; int qc = q < NTOK ? q : NTOK - 1;
        *reinterpret_cast<float4*>(&Bb[brow][c2*8]) =
            *reinterpret_cast<const float4*>(&bfp[((size_t)h*NTOK + qc)*BIAS_LD + kvt*64 + c2*8]);
      }
    }
    __syncthreads();

    // S = Q @ K^T
    f32x4 s[4];
    #pragma unroll
    for (int nt = 0; nt < 4; ++nt) {
      half8 bk = *reinterpret_cast<half8*>(&Ks[nt*16 + (lane & 15)][(lane >> 4)*8]);
      f32x4 z = {0.f,0.f,0.f,0.f};
      s[nt] = __builtin_amdgcn_mfma_f32_16x16x32_f16(aq, bk, z, 0, 0, 0);
    }

    // bias (from LDS) + mask + row max
    float sv[4][4]; float rmax[4];
    #pragma unroll
    for (int r = 0; r < 4; ++r) rmax[r] = -3.0e38f;
    #pragma unroll
    for (int nt = 0; nt < 4; ++nt) {
      int kv = kvt*64 + nt*16 + (lane & 15);
      bool kvok = kv < NTOK;
      #pragma unroll
      for (int r = 0; r < 4; ++r) {
        int ql = wave*16 + (lane >> 4)*4 + r;
        float x = s[nt][r] + (float)Bb[ql][nt*16 + (lane & 15)];
        x = kvok ? x : -1.0e30f;
        sv[nt][r] = x;
        rmax[r] = fmaxf(rmax[r], x);
      }
    }
    #pragma unroll
    for (int r = 0; r < 4; ++r) {
      float v = rmax[r];
      v = fmaxf(v, __shfl_xor(v, 1));
      v = fmaxf(v, __shfl_xor(v, 2));
      v = fmaxf(v, __shfl_xor(v, 4));
      v = fmaxf(v, __shfl_xor(v, 8));
      rmax[r] = v;
    }
    #pragma unroll
    for (int r = 0; r < 4; ++r) {
      float mnew = fmaxf(m_run[r], rmax[r]);
      float sf = __expf(m_run[r] - mnew);
      m_run[r] = mnew;
      l_run[r] *= sf;
      o0[r] *= sf; o1[r] *= sf;
      float rs = 0.f;
      int qrow = wave*16 + (lane >> 4)*4 + r;
      #pragma unroll
      for (int nt = 0; nt < 4; ++nt) {
        float p = __expf(sv[nt][r] - mnew);
        rs += p;
        Ps[qrow][nt*16 + (lane & 15)] = (f16)p;
      }
      rs += __shfl_xor(rs, 1);
      rs += __shfl_xor(rs, 2);
      rs += __shfl_xor(rs, 4);
      rs += __shfl_xor(rs, 8);
      l_run[r] += rs;
    }

    // PV: O += P @ V   (P re-read within same wave rows; no barrier needed)
    half8 ap0 = *reinterpret_cast<half8*>(&Ps[wave*16 + (lane & 15)][(lane >> 4)*8]);
    half8 ap1 = *reinterpret_cast<half8*>(&Ps[wave*16 + (lane & 15)][32 + (lane >> 4)*8]);
    half8 bv;
    bv = *reinterpret_cast<half8*>(&Vs[(lane & 15)][(lane >> 4)*8]);
    o0 = __builtin_amdgcn_mfma_f32_16x16x32_f16(ap0, bv, o0, 0, 0, 0);
    bv = *reinterpret_cast<half8*>(&Vs[(lane & 15)][32 + (lane >> 4)*8]);
    o0 = __builtin_amdgcn_mfma_f32_16x16x32_f16(ap1, bv, o0, 0, 0, 0);
    bv = *reinterpret_cast<half8*>(&Vs[16 + (lane & 15)][(lane >> 4)*8]);
    o1 = __builtin_amdgcn_mfma_f32_16x16x32_f16(ap0, bv, o1, 0, 0, 0);
    bv = *reinterpret_cast<half8*>(&Vs[16 + (lane & 15)][32 + (lane >> 4)*8]);
    o1 = __builtin_amdgcn_mfma_f32_16x16x32_f16(ap1, bv, o1, 0, 0, 0);
    __syncthreads();  // all waves done with Ks/Vs/Bb before restage
  }

  // epilogue: normalize, bounce through Ps (same-wave rows), coalesced f16 stores
  #pragma unroll
  for (int r = 0; r < 4; ++r) {
    int qrow = wave*16 + (lane >> 4)*4 + r;
    float inv = 1.f / l_run[r];
    Ps[qrow][(lane & 15)]      = (f16)(o0[r] * inv);
    Ps[qrow][16 + (lane & 15)] = (f16)(o1[r] * inv);
  }
  {
    int row = tid >> 2, ch = tid & 3;     // row within this wave's 16-row band
    int q = qt*64 + row;
    if (q < NTOK) {
      float4 v = *reinterpret_cast<float4*>(&Ps[row][ch*8]);
      *reinterpret_cast<float4*>(&ab[((size_t)b*NTOK + q)*KDIM + h*HD + ch*8]) = v;
    }
  }
}

// ---------------- K3: projection GEMM + bias (fp32 out, 64B-coalesced) ----------------
__global__ __launch_bounds__(256) void proj_gemm(const f16* __restrict__ ab,
                                                 const f16* __restrict__ wp,
                                                 const float* __restrict__ proj_b,
                                                 float* __restrict__ out) {
  __shared__ __align__(16) f16 smem[16384];
  f16* As = smem;
  f16* Bs = smem + 8192;
  const int ntile = blockIdx.x, mtile = blockIdx.y;
  f32x4 acc[4][4];
  gemm128_body(ab, wp, mtile, ntile, acc, As, Bs);
  const int lane = threadIdx.x & 63;
  const int w = threadIdx.x >> 6;
  const int wm = w >> 1, wn = w & 1;
  #pragma unroll
  for (int ni = 0; ni < 4; ++ni) {
    int j = ntile*128 + wn*64 + ni*16 + (lane & 15);
    float pb = proj_b[j];
    #pragma unroll
    for (int mi = 0; mi < 4; ++mi)
      #pragma unroll
      for (int r = 0; r < 4; ++r) {
        int m = mtile*128 + wm*64 + mi*16 + (lane >> 4)*4 + r;
        out[(size_t)m*KDIM + j] = acc[mi][ni][r] + pb;
      }
  }
}

// ---------------- host ----------------
extern "C" void kernel_launch(void* const* d_in, const int* in_sizes, int n_in,
                              void* d_out, int out_size, void* d_ws, size_t ws_size,
                              hipStream_t stream) {
  const float* x          = (const float*)d_in[0];
  const float* qkv_w      = (const float*)d_in[1];
  const float* qkv_b      = (const float*)d_in[2];
  const float* proj_w     = (const float*)d_in[3];
  const float* proj_b     = (const float*)d_in[4];
  const float* bias_table = (const float*)d_in[5];
  const int*   rel_index  = (const int*)d_in[6];

  const size_t M = (size_t)NBATCH * NTOK;  // 43904
  char* p = (char*)d_ws;
  auto alloc = [&](size_t bytes) { void* r = (void*)p; p += (bytes + 255) & ~(size_t)255; return r; };
  f16* xb   = (f16*)alloc(M * KDIM * 2);                          // x f16 (later reused as ab)
  f16* wq   = (f16*)alloc((size_t)3 * KDIM * KDIM * 2);
  f16* wp   = (f16*)alloc((size_t)KDIM * KDIM * 2);
  f16* qkvb = (f16*)alloc(M * QKV_LD * 2);                        // fused qkv output
  f16* vt   = (f16*)alloc((size_t)NBATCH*NHEADS*HD*KDIM*2);       // v transposed
  f16* bfp  = (f16*)alloc((size_t)NHEADS*NTOK*BIAS_LD*2);         // bias padded [h][343][384]
  f16* ab   = xb;  // alias: xb dead after qkv_gemm

  cvt_f32_f16<<<4096, 256, 0, stream>>>(x, xb, (int)(M * KDIM / 4));
  cvt_f32_f16<<<432, 256, 0, stream>>>(qkv_w, wq, 3 * KDIM * KDIM / 4);
  cvt_f32_f16<<<144, 256, 0, stream>>>(proj_w, wp, KDIM * KDIM / 4);
  bias_expand<<<dim3(NTOK, NHEADS), 384, 0, stream>>>(bias_table, rel_index, bfp);
  qkv_gemm<<<dim3(9, 343), 256, 0, stream>>>(xb, wq, qkv_b, qkvb);
  vtrans<<<dim3(6, NHEADS, NBATCH), 256, 0, stream>>>(qkvb, vt);
  attn_kernel<<<dim3(6, NHEADS, NBATCH), 256, 0, stream>>>(qkvb, vt, bfp, ab);
  proj_gemm<<<dim3(3, 343), 256, 0, stream>>>(ab, wp, proj_b, (float*)d_out);
}

// Round 4
// 366.808 us; speedup vs baseline: 1.6576x; 1.2113x over previous
//
#include <hip/hip_runtime.h>

typedef _Float16 f16;
typedef _Float16 half8 __attribute__((ext_vector_type(8)));
typedef _Float16 half4 __attribute__((ext_vector_type(4)));
typedef __fp16 fp16x2 __attribute__((ext_vector_type(2)));
typedef float f32x4 __attribute__((ext_vector_type(4)));

#define NTOK 343
#define NHEADS 12
#define NBATCH 128
#define HD 32
#define KDIM 384
#define QKV_LD 1152
#define LOG2E 1.4426950408889634f

static __device__ __forceinline__ void gload16(const f16* g, f16* l) {
  __builtin_amdgcn_global_load_lds((const __attribute__((address_space(1))) void*)g,
                                   (__attribute__((address_space(3))) void*)l, 16, 0, 0);
}

// ---------------- K0: fp32 -> fp16 convert ----------------
__global__ __launch_bounds__(256) void cvt_f32_f16(const float* __restrict__ src,
                                                   f16* __restrict__ dst, int n4) {
  int stride = gridDim.x * blockDim.x;
  for (int i = blockIdx.x * blockDim.x + threadIdx.x; i < n4; i += stride) {
    float4 v = reinterpret_cast<const float4*>(src)[i];
    half4 h;
    h[0] = (f16)v.x; h[1] = (f16)v.y; h[2] = (f16)v.z; h[3] = (f16)v.w;
    reinterpret_cast<half4*>(dst)[i] = h;
  }
}

// ---------------- K0b: bias pre-permute into MFMA C^T-fragment order ----------------
// bperm[h][qt][kvt][wave][lane][16] f16; elem nt*4+r = bias(q=qt*64+wave*16+(lane&15),
// kv=kvt*64+nt*16+(lane>>4)*4+r) * log2e; kv>=343 -> -30000 (mask baked in).
__global__ __launch_bounds__(256) void bperm_gen(const float* __restrict__ table,
                                                 const int* __restrict__ rel,
                                                 f16* __restrict__ out) {
  const int qt = blockIdx.x / 6, kvt = blockIdx.x % 6, h = blockIdx.y;
  const int wave = threadIdx.x >> 6, lane = threadIdx.x & 63;
  const int qi = lane & 15, G = lane >> 4;
  int q = qt*64 + wave*16 + qi; int qc = q < NTOK ? q : NTOK - 1;
  f16 vals[16];
  #pragma unroll
  for (int nt = 0; nt < 4; ++nt)
    #pragma unroll
    for (int r = 0; r < 4; ++r) {
      int kv = kvt*64 + nt*16 + G*4 + r;
      float v = (kv < NTOK) ? table[rel[qc*NTOK + kv]*NHEADS + h] * LOG2E : -30000.0f;
      vals[nt*4+r] = (f16)v;
    }
  f16* dst = out + ((((size_t)h*6 + qt)*6 + kvt)*4 + wave)*1024 + lane*16;
  *reinterpret_cast<half8*>(dst)     = *reinterpret_cast<half8*>(&vals[0]);
  *reinterpret_cast<half8*>(dst + 8) = *reinterpret_cast<half8*>(&vals[8]);
}

// ---------------- 128x128 GEMM body (global_load_lds staging, linear LDS) ----------------
__device__ __forceinline__ void gemm128_body(const f16* __restrict__ A,
                                             const f16* __restrict__ Bw,
                                             int mtile, int ntile,
                                             f32x4 acc[4][4],
                                             f16* As, f16* Bs) {
  const int tid = threadIdx.x;
  const int lane = tid & 63;
  const int w = tid >> 6;
  const int wm = w >> 1, wn = w & 1;

  #pragma unroll
  for (int i = 0; i < 4; ++i)
    #pragma unroll
    for (int j = 0; j < 4; ++j) { f32x4 z = {0.f,0.f,0.f,0.f}; acc[i][j] = z; }

  const int lrow = w * 8 + (lane >> 3);
  const int lcol = (lane & 7) * 8;
  const f16* Ab = A + (size_t)(mtile*128 + lrow) * KDIM + lcol;
  const f16* Bb = Bw + (size_t)(ntile*128 + lrow) * KDIM + lcol;

  for (int k0 = 0; k0 < KDIM; k0 += 64) {
    __syncthreads();
    #pragma unroll
    for (int rnd = 0; rnd < 4; ++rnd) {
      gload16(Ab + (size_t)rnd*32*KDIM + k0, As + rnd*2048 + w*512);
      gload16(Bb + (size_t)rnd*32*KDIM + k0, Bs + rnd*2048 + w*512);
    }
    __syncthreads();
    #pragma unroll
    for (int kk = 0; kk < 2; ++kk) {
      half8 af[4], bf[4];
      #pragma unroll
      for (int mi = 0; mi < 4; ++mi)
        af[mi] = *reinterpret_cast<half8*>(&As[(wm*64 + mi*16 + (lane & 15))*64 + kk*32 + (lane >> 4)*8]);
      #pragma unroll
      for (int ni = 0; ni < 4; ++ni)
        bf[ni] = *reinterpret_cast<half8*>(&Bs[(wn*64 + ni*16 + (lane & 15))*64 + kk*32 + (lane >> 4)*8]);
      #pragma unroll
      for (int mi = 0; mi < 4; ++mi)
        #pragma unroll
        for (int ni = 0; ni < 4; ++ni)
          acc[mi][ni] = __builtin_amdgcn_mfma_f32_16x16x32_f16(af[mi], bf[ni], acc[mi][ni], 0, 0, 0);
    }
  }
}

// ---------------- K1: QKV GEMM -> qkvb[m][1152] (q pre-scaled by scale*log2e) ----------------
__global__ __launch_bounds__(256) void qkv_gemm(const f16* __restrict__ xb,
                                                const f16* __restrict__ wq,
                                                const float* __restrict__ qkv_b,
                                                f16* __restrict__ qkvb) {
  __shared__ __align__(16) f16 smem[17408];
  f16* As = smem;
  f16* Bs = smem + 8192;
  // bijective XCD swizzle (m204), nwg=3087: q=385,r=7
  int orig = blockIdx.x + 9*blockIdx.y;
  int xcd = orig & 7, off = orig >> 3;
  int wg = (xcd < 7 ? xcd*386 : 2702 + (xcd-7)*385) + off;
  const int ntile = wg % 9, mtile = wg / 9;

  f32x4 acc[4][4];
  gemm128_body(xb, wq, mtile, ntile, acc, As, Bs);

  const int tid = threadIdx.x;
  const int lane = tid & 63;
  const int w = tid >> 6;
  const int wm = w >> 1, wn = w & 1;
  const float scale = (ntile < 3) ? 0.17677669529663687f * LOG2E : 1.0f;

  float bj[4];
  #pragma unroll
  for (int ni = 0; ni < 4; ++ni)
    bj[ni] = qkv_b[ntile*128 + wn*64 + ni*16 + (lane & 15)];

  __syncthreads();
  f16* Cs = smem;
  #pragma unroll
  for (int ni = 0; ni < 4; ++ni) {
    int col = wn*64 + ni*16 + (lane & 15);
    #pragma unroll
    for (int mi = 0; mi < 4; ++mi)
      #pragma unroll
      for (int r = 0; r < 4; ++r) {
        int row = wm*64 + mi*16 + (lane >> 4)*4 + r;
        Cs[row*136 + col] = (f16)((acc[mi][ni][r] + bj[ni]) * scale);
      }
  }
  __syncthreads();
  #pragma unroll
  for (int p = 0; p < 8; ++p) {
    int row = p*16 + (tid >> 4);
    int col = (tid & 15) * 8;
    float4 v = *reinterpret_cast<float4*>(&Cs[row*136 + col]);
    *reinterpret_cast<float4*>(&qkvb[(size_t)(mtile*128 + row)*QKV_LD + ntile*128 + col]) = v;
  }
}

// ---------------- K1b: V transpose ----------------
__global__ __launch_bounds__(256) void vtrans(const f16* __restrict__ qkvb,
                                              f16* __restrict__ vt) {
  __shared__ __align__(16) f16 T[64][40];
  const int tid = threadIdx.x;
  const int nt = blockIdx.x, h = blockIdx.y, b = blockIdx.z;
  {
    int row = tid >> 2, ch = tid & 3;
    int n = nt*64 + row; int nc = n < NTOK ? n : NTOK - 1;
    *reinterpret_cast<float4*>(&T[row][ch*8]) =
        *reinterpret_cast<const float4*>(&qkvb[((size_t)b*NTOK + nc)*QKV_LD + 2*KDIM + h*HD + ch*8]);
  }
  __syncthreads();
  int d = tid >> 3, c2 = tid & 7;
  half8 o;
  #pragma unroll
  for (int e = 0; e < 8; ++e) o[e] = T[c2*8 + e][d];
  *reinterpret_cast<half8*>(&vt[((size_t)(b*NHEADS + h)*HD + d)*KDIM + nt*64 + c2*8]) = o;
}

// ---------------- K2: fused flash attention, swapped-QK^T layout ----------------
// grid flat 9216 = (qt6, h12, b128); 4 waves; lane owns q=lane&15, group G=lane>>4.
__global__ __launch_bounds__(256) void attn_kernel(const f16* __restrict__ qkvb,
                                                   const f16* __restrict__ vt,
                                                   const f16* __restrict__ bperm,
                                                   f16* __restrict__ ab) {
  __shared__ __align__(16) f16 Qs[64][40];
  __shared__ __align__(16) f16 Ks[64][40];
  __shared__ __align__(16) f16 Vs[32][72];
  __shared__ __align__(16) f16 PB[4][2][4][144];   // [wave][slice][Gt][16q*8e + pad]
  const int tid = threadIdx.x;
  const int lane = tid & 63;
  const int wave = tid >> 6;
  const int qi = lane & 15;
  const int G = lane >> 4;
  // XCD swizzle (9216 % 8 == 0)
  int orig = blockIdx.x + 6*blockIdx.y + 72*blockIdx.z;
  int wg = (orig & 7) * 1152 + (orig >> 3);
  const int qt = wg % 6;
  const int h  = (wg / 6) % 12;
  const int b  = wg / 72;
  const size_t bh = (size_t)b * NHEADS + h;

  {  // stage Q tile (64 x 32)
    int row = tid >> 2, ch = tid & 3;
    int n = qt*64 + row; n = n < NTOK ? n : NTOK - 1;
    *reinterpret_cast<float4*>(&Qs[row][ch*8]) =
        *reinterpret_cast<const float4*>(&qkvb[((size_t)b*NTOK + n)*QKV_LD + h*HD + ch*8]);
  }
  __syncthreads();
  half8 aq = *reinterpret_cast<half8*>(&Qs[wave*16 + qi][G*8]);   // Q B-frag: n=qi, k=G*8+e

  const f16* bp = bperm + ((((size_t)h*6 + qt)*6)*4 + wave)*1024 + lane*16;

  // T14 prefetch: tile 0 K/V/bias into regs
  const int krow = tid >> 2, kch = tid & 3;
  const int vd = tid >> 3, vch = tid & 7;
  float4 kreg, vreg; half8 bb0, bb1;
  {
    int n = krow; n = n < NTOK ? n : NTOK - 1;
    kreg = *reinterpret_cast<const float4*>(&qkvb[((size_t)b*NTOK + n)*QKV_LD + KDIM + h*HD + kch*8]);
    vreg = *reinterpret_cast<const float4*>(&vt[(bh*HD + vd)*KDIM + vch*8]);
    bb0 = *reinterpret_cast<const half8*>(bp);
    bb1 = *reinterpret_cast<const half8*>(bp + 8);
  }

  float m_run = -3.0e38f, l_run = 0.f;
  f32x4 o0 = {0.f,0.f,0.f,0.f}, o1 = {0.f,0.f,0.f,0.f};

  for (int kvt = 0; kvt < 6; ++kvt) {
    __syncthreads();   // all waves done reading Ks/Vs of previous tile
    *reinterpret_cast<float4*>(&Ks[krow][kch*8]) = kreg;
    *reinterpret_cast<float4*>(&Vs[vd][vch*8]) = vreg;
    half8 cb0 = bb0, cb1 = bb1;
    if (kvt < 5) {     // prefetch next tile during this tile's compute
      int n = (kvt+1)*64 + krow; n = n < NTOK ? n : NTOK - 1;
      kreg = *reinterpret_cast<const float4*>(&qkvb[((size_t)b*NTOK + n)*QKV_LD + KDIM + h*HD + kch*8]);
      vreg = *reinterpret_cast<const float4*>(&vt[(bh*HD + vd)*KDIM + (kvt+1)*64 + vch*8]);
      bb0 = *reinterpret_cast<const half8*>(bp + (kvt+1)*4096);
      bb1 = *reinterpret_cast<const half8*>(bp + (kvt+1)*4096 + 8);
    }
    __syncthreads();   // Ks/Vs ready

    // S^T = K @ Q^T : lane -> S[kv=nt*16+G*4+r][q=qi]
    f32x4 s[4];
    half8 ak0 = *reinterpret_cast<half8*>(&Ks[ 0 + qi][G*8]);
    half8 ak1 = *reinterpret_cast<half8*>(&Ks[16 + qi][G*8]);
    half8 ak2 = *reinterpret_cast<half8*>(&Ks[32 + qi][G*8]);
    half8 ak3 = *reinterpret_cast<half8*>(&Ks[48 + qi][G*8]);
    f32x4 z = {0.f,0.f,0.f,0.f};
    __builtin_amdgcn_s_setprio(1);
    s[0] = __builtin_amdgcn_mfma_f32_16x16x32_f16(ak0, aq, z, 0, 0, 0);
    s[1] = __builtin_amdgcn_mfma_f32_16x16x32_f16(ak1, aq, z, 0, 0, 0);
    s[2] = __builtin_amdgcn_mfma_f32_16x16x32_f16(ak2, aq, z, 0, 0, 0);
    s[3] = __builtin_amdgcn_mfma_f32_16x16x32_f16(ak3, aq, z, 0, 0, 0);
    __builtin_amdgcn_s_setprio(0);

    // + bias (log2e-folded; kv>=343 masked via -30000)
    #pragma unroll
    for (int nt = 0; nt < 4; ++nt)
      #pragma unroll
      for (int r = 0; r < 4; ++r)
        s[nt][r] += (float)((nt < 2) ? cb0[nt*4+r] : cb1[(nt-2)*4+r]);

    // row max: 15 local + 2 shfl (lanes qi, qi+16, qi+32, qi+48 share q-row)
    float mx0 = fmaxf(fmaxf(s[0][0], s[0][1]), fmaxf(s[0][2], s[0][3]));
    float mx1 = fmaxf(fmaxf(s[1][0], s[1][1]), fmaxf(s[1][2], s[1][3]));
    float mx2 = fmaxf(fmaxf(s[2][0], s[2][1]), fmaxf(s[2][2], s[2][3]));
    float mx3 = fmaxf(fmaxf(s[3][0], s[3][1]), fmaxf(s[3][2], s[3][3]));
    float mx = fmaxf(fmaxf(mx0, mx1), fmaxf(mx2, mx3));
    mx = fmaxf(mx, __shfl_xor(mx, 16));
    mx = fmaxf(mx, __shfl_xor(mx, 32));

    float mnew = fmaxf(m_run, mx);
    float corr = exp2f(m_run - mnew);
    m_run = mnew;
    l_run *= corr;
    #pragma unroll
    for (int r = 0; r < 4; ++r) { o0[r] *= corr; o1[r] *= corr; }

    float ts = 0.f;
    #pragma unroll
    for (int nt = 0; nt < 4; ++nt)
      #pragma unroll
      for (int r = 0; r < 4; ++r) {
        float pv = exp2f(s[nt][r] - mnew);
        s[nt][r] = pv;
        ts += pv;
      }
    ts += __shfl_xor(ts, 16);
    ts += __shfl_xor(ts, 32);
    l_run += ts;

    // pack P -> PB in B-frag order: PB[w][s][Gt][qi*8 + e]
    #pragma unroll
    for (int nt = 0; nt < 4; ++nt) {
      int Gt = 2*(nt & 1) + (G >> 1);
      int sN = nt >> 1;
      #pragma unroll
      for (int rr = 0; rr < 2; ++rr) {
        fp16x2 ph = __builtin_amdgcn_cvt_pkrtz(s[nt][2*rr], s[nt][2*rr+1]);
        int eb = (G & 1)*4 + 2*rr;
        *reinterpret_cast<fp16x2*>(&PB[wave][sN][Gt][qi*8 + eb]) = ph;
      }
    }

    // PV: O^T[d][q] += V^T[d][kv] * P[q][kv]  (wave-local PB, no barrier)
    half8 pb0 = *reinterpret_cast<half8*>(&PB[wave][0][G][qi*8]);
    half8 pb1 = *reinterpret_cast<half8*>(&PB[wave][1][G][qi*8]);
    half8 av00 = *reinterpret_cast<half8*>(&Vs[qi][G*8]);
    half8 av01 = *reinterpret_cast<half8*>(&Vs[qi][32 + G*8]);
    half8 av10 = *reinterpret_cast<half8*>(&Vs[16 + qi][G*8]);
    half8 av11 = *reinterpret_cast<half8*>(&Vs[16 + qi][32 + G*8]);
    __builtin_amdgcn_s_setprio(1);
    o0 = __builtin_amdgcn_mfma_f32_16x16x32_f16(av00, pb0, o0, 0, 0, 0);
    o0 = __builtin_amdgcn_mfma_f32_16x16x32_f16(av01, pb1, o0, 0, 0, 0);
    o1 = __builtin_amdgcn_mfma_f32_16x16x32_f16(av10, pb0, o1, 0, 0, 0);
    o1 = __builtin_amdgcn_mfma_f32_16x16x32_f16(av11, pb1, o1, 0, 0, 0);
    __builtin_amdgcn_s_setprio(0);
  }

  // epilogue: normalize, bounce via Qs (own-wave rows), coalesced stores
  float inv = 1.f / l_run;
  #pragma unroll
  for (int rr = 0; rr < 2; ++rr) {
    fp16x2 a = __builtin_amdgcn_cvt_pkrtz(o0[2*rr]*inv, o0[2*rr+1]*inv);
    *reinterpret_cast<fp16x2*>(&Qs[wave*16 + qi][G*4 + 2*rr]) = a;
    fp16x2 c = __builtin_amdgcn_cvt_pkrtz(o1[2*rr]*inv, o1[2*rr+1]*inv);
    *reinterpret_cast<fp16x2*>(&Qs[wave*16 + qi][16 + G*4 + 2*rr]) = c;
  }
  {
    int row = lane >> 2, ch = lane & 3;
    int q = qt*64 + wave*16 + row;
    if (q < NTOK) {
      float4 v = *reinterpret_cast<float4*>(&Qs[wave*16 + row][ch*8]);
      *reinterpret_cast<float4*>(&ab[((size_t)b*NTOK + q)*KDIM + h*HD + ch*8]) = v;
    }
  }
}

// ---------------- K3: projection GEMM + bias ----------------
__global__ __launch_bounds__(256) void proj_gemm(const f16* __restrict__ ab,
                                                 const f16* __restrict__ wp,
                                                 const float* __restrict__ proj_b,
                                                 float* __restrict__ out) {
  __shared__ __align__(16) f16 smem[16384];
  f16* As = smem;
  f16* Bs = smem + 8192;
  // swizzle nwg=1029: q=128,r=5
  int orig = blockIdx.x + 3*blockIdx.y;
  int xcd = orig & 7, off = orig >> 3;
  int wg = (xcd < 5 ? xcd*129 : 645 + (xcd-5)*128) + off;
  const int ntile = wg % 3, mtile = wg / 3;

  f32x4 acc[4][4];
  gemm128_body(ab, wp, mtile, ntile, acc, As, Bs);
  const int lane = threadIdx.x & 63;
  const int w = threadIdx.x >> 6;
  const int wm = w >> 1, wn = w & 1;
  #pragma unroll
  for (int ni = 0; ni < 4; ++ni) {
    int j = ntile*128 + wn*64 + ni*16 + (lane & 15);
    float pb = proj_b[j];
    #pragma unroll
    for (int mi = 0; mi < 4; ++mi)
      #pragma unroll
      for (int r = 0; r < 4; ++r) {
        int m = mtile*128 + wm*64 + mi*16 + (lane >> 4)*4 + r;
        out[(size_t)m*KDIM + j] = acc[mi][ni][r] + pb;
      }
  }
}

// ---------------- host ----------------
extern "C" void kernel_launch(void* const* d_in, const int* in_sizes, int n_in,
                              void* d_out, int out_size, void* d_ws, size_t ws_size,
                              hipStream_t stream) {
  const float* x          = (const float*)d_in[0];
  const float* qkv_w      = (const float*)d_in[1];
  const float* qkv_b      = (const float*)d_in[2];
  const float* proj_w     = (const float*)d_in[3];
  const float* proj_b     = (const float*)d_in[4];
  const float* bias_table = (const float*)d_in[5];
  const int*   rel_index  = (const int*)d_in[6];

  const size_t M = (size_t)NBATCH * NTOK;
  char* p = (char*)d_ws;
  auto alloc = [&](size_t bytes) { void* r = (void*)p; p += (bytes + 255) & ~(size_t)255; return r; };
  f16* xb    = (f16*)alloc(M * KDIM * 2);
  f16* wq    = (f16*)alloc((size_t)3 * KDIM * KDIM * 2);
  f16* wp    = (f16*)alloc((size_t)KDIM * KDIM * 2);
  f16* qkvb  = (f16*)alloc(M * QKV_LD * 2);
  f16* vt    = (f16*)alloc((size_t)NBATCH*NHEADS*HD*KDIM*2);
  f16* bperm = (f16*)alloc((size_t)NHEADS*6*6*4*64*16*2);
  f16* ab    = xb;  // alias: xb dead after qkv_gemm

  cvt_f32_f16<<<4096, 256, 0, stream>>>(x, xb, (int)(M * KDIM / 4));
  cvt_f32_f16<<<432, 256, 0, stream>>>(qkv_w, wq, 3 * KDIM * KDIM / 4);
  cvt_f32_f16<<<144, 256, 0, stream>>>(proj_w, wp, KDIM * KDIM / 4);
  bperm_gen<<<dim3(36, NHEADS), 256, 0, stream>>>(bias_table, rel_index, bperm);
  qkv_gemm<<<dim3(9, 343), 256, 0, stream>>>(xb, wq, qkv_b, qkvb);
  vtrans<<<dim3(6, NHEADS, NBATCH), 256, 0, stream>>>(qkvb, vt);
  attn_kernel<<<dim3(6, NHEADS, NBATCH), 256, 0, stream>>>(qkvb, vt, bperm, ab);
  proj_gemm<<<dim3(3, 343), 256, 0, stream>>>(ab, wp, proj_b, (float*)d_out);
}